// Round 3
// baseline (1871.005 us; speedup 1.0000x reference)
//
#include <hip/hip_runtime.h>
#include <stdint.h>

// Problem dims
#define NB   64      // batch
#define NT   256     // timesteps
#define NS   512     // input feature (state)
#define NH   1024    // hidden
#define NG   4096    // 4*NH (gates)
#define NHD  512     // dense1 width
#define NA   64      // action size
#define NO   64      // n_output

typedef float f32x4  __attribute__((ext_vector_type(4)));
typedef short bf16x8 __attribute__((ext_vector_type(8)));
typedef int   i32x4  __attribute__((ext_vector_type(4)));

__device__ __forceinline__ unsigned short f2bf(float f) {
    union { float f; unsigned u; } a; a.f = f;
    unsigned u = a.u;
    return (unsigned short)((u + 0x7fffu + ((u >> 16) & 1u)) >> 16);   // RNE
}
__device__ __forceinline__ float bf2f(unsigned short h) {
    union { unsigned u; float f; } a; a.u = ((unsigned)h) << 16; return a.f;
}
__device__ __forceinline__ float sigm(float x) {
    return __fdividef(1.0f, 1.0f + __expf(-x));
}
__device__ __forceinline__ float tanh_f(float x) {
    float e = __expf(-2.0f * fabsf(x));
    float r = __fdividef(1.0f - e, 1.0f + e);
    return x >= 0.0f ? r : -r;
}

// sc1 load: bypasses the non-coherent per-XCD L2 -> reads the coherence point.
#define GLD(dst, base, off) \
    asm volatile("global_load_dwordx4 %0, %1, off offset:" #off " sc1" \
                 : "=v"(dst) : "v"(base) : "memory")

// h-phase chunk (r13 layout: 1 m-tile, 4 n-tiles, Wh-lo from LDS).
// 8 h loads outstanding at phase start; chunk ks retired at vmcnt <= 7-ks.
// whh from VGPR; whl read per-chunk from LDS (4x ds_read_b128, hidden
// behind the inter-chunk sc1 return gaps; compiler inserts the lgkmcnt
// before MFMA use). The vmcnt asm ties q[ks] so the dependent MFMAs
// can't hoist above it. No #pragma in macro bodies (r6).
#define HKS(WN, ks)                                                              \
    {                                                                            \
        asm volatile("s_waitcnt vmcnt(" #WN ")" : "+v"(q[ks]));                  \
        union { i32x4 i; bf16x8 v; } u0; u0.i = q[ks];                           \
        bf16x8 fh = u0.v;                                                        \
        bf16x8 l0 = whl_lds[w][0][ks][lane];                                     \
        bf16x8 l1 = whl_lds[w][1][ks][lane];                                     \
        bf16x8 l2 = whl_lds[w][2][ks][lane];                                     \
        bf16x8 l3 = whl_lds[w][3][ks][lane];                                     \
        acc[0] = __builtin_amdgcn_mfma_f32_16x16x32_bf16(fh, whh[0][ks], acc[0], 0, 0, 0); \
        acc[1] = __builtin_amdgcn_mfma_f32_16x16x32_bf16(fh, whh[1][ks], acc[1], 0, 0, 0); \
        acc[2] = __builtin_amdgcn_mfma_f32_16x16x32_bf16(fh, whh[2][ks], acc[2], 0, 0, 0); \
        acc[3] = __builtin_amdgcn_mfma_f32_16x16x32_bf16(fh, whh[3][ks], acc[3], 0, 0, 0); \
        acc[0] = __builtin_amdgcn_mfma_f32_16x16x32_bf16(fh, l0, acc[0], 0, 0, 0); \
        acc[1] = __builtin_amdgcn_mfma_f32_16x16x32_bf16(fh, l1, acc[1], 0, 0, 0); \
        acc[2] = __builtin_amdgcn_mfma_f32_16x16x32_bf16(fh, l2, acc[2], 0, 0, 0); \
        acc[3] = __builtin_amdgcn_mfma_f32_16x16x32_bf16(fh, l3, acc[3], 0, 0, 0); \
    }

// Workspace layout (bytes):
//   [0)       hpk : 2 x 64 x 1024 bf16 = 262144  (h bf16-only, dbl-buffered)
//   [262144)  hF32: 64 x 1024 f32      = 262144
//   [524288)  hid : 64 x 512 f32       = 131072
//   [655360)  flags: 4 groups x 128 i32 = 2048   (per-WAVE flags, r15)
#define WS_HPK   0
#define WS_HF32  262144
#define WS_HID   524288
#define WS_FLG   655360

__global__ void prologue(unsigned int* __restrict__ hpk32,
                         unsigned int* __restrict__ flg32) {
    int idx = blockIdx.x * blockDim.x + threadIdx.x;   // 65536 threads
    hpk32[idx] = 0u;            // 65536 u32 = 131072 bf16 = both parities
    if (idx < 512) flg32[idx] = 0u;
}

// Persistent LSTM recurrence. Weights & x: double-bf16 hi/lo (exact);
// h exchange: bf16-ONLY (r12). 4 groups x 64 blocks (r13/r14, measured
// 5.37 us/step).
// r15: per-WAVE early flag publish. The old publish path was:
// h-store -> block barrier (waits store-ack of BOTH epilogue waves AND
// arrival of waves 2,3) -> tid0 flag. New: each epilogue wave drains its
// OWN vmcnt(0) and publishes flag[bi*2+w] immediately; barrier-3 is
// deleted (3 -> 2 barriers/loop). Consumers poll 128 flags/group as 64
// ull pairs — the exact r12-proven poll pattern. Waves 2,3 have no
// publish duty, so their earlier x-prefetch cannot delay a flag (the
// r11 sensitivity was about prefetch-before-publish on the same wave).
// Group g: batches [16g,16g+16) (ONE m-tile); block bi: h-cols
// [16bi,16bi+16) x 4 gates as 4 n-tiles (nt == gate); wave w: K-slice.
// Weight storage: whh+wx hi/lo in VGPR (256); Wh-lo frags in LDS (128 KB,
// same-wave same-lane write/read -> no barrier).
// PLAIN launch (cooperative fails silently — r2). 256 blocks == 256 CUs;
// 145 KiB LDS forces 1 block/CU.
__global__ __launch_bounds__(256, 1) void lstm_persist(
    const float* __restrict__ x, const float* __restrict__ Wx,
    const float* __restrict__ Wh, const float* __restrict__ bias,
    unsigned short* __restrict__ hpack, float* __restrict__ hF32,
    int* __restrict__ flags)
{
    const int g    = blockIdx.x >> 6;    // group 0..3
    const int bi   = blockIdx.x & 63;    // block-in-group 0..63
    const int tid  = threadIdx.x;
    const int w    = tid >> 6;
    const int lane = tid & 63;
    const int lm   = lane & 15;   // A: m(batch row) ; B: n ; D: col
    const int lq   = lane >> 4;   // k-quad

    // Wh-lo fragments: [wave][nt][ks][lane] of bf16x8 = 128 KiB.
    // Each wave reads ONLY its own [w] slice -> no barrier needed.
    __shared__ bf16x8 whl_lds[4][4][8][64];
    __shared__ float zl[4][4][16][17];   // [wave][nt][row][col] (+1 pad)

    // ---- one-time: weight B-fragments into registers / LDS ----
    // B-frag (16x16x32): lane holds B[k = lq*8 + j][n = lm], j = 0..7
    bf16x8 wxh[4][4], wxl[4][4];   // [nt][kstep] x-path, K=512/4waves
    bf16x8 whh[4][8];              // [nt][kstep] h-path hi, K=1024/4waves
    #pragma unroll
    for (int nt = 0; nt < 4; ++nt) {
        const int zc = nt * NH + bi * 16 + lm;   // nt == gate
        #pragma unroll
        for (int ks = 0; ks < 4; ++ks)
            #pragma unroll
            for (int j = 0; j < 8; ++j) {
                int k = w * 128 + ks * 32 + lq * 8 + j;
                float v = Wx[(size_t)k * NG + zc];
                unsigned short h = f2bf(v);
                wxh[nt][ks][j] = (short)h;
                wxl[nt][ks][j] = (short)f2bf(v - bf2f(h));
            }
        #pragma unroll
        for (int ks = 0; ks < 8; ++ks) {
            bf16x8 lo;
            #pragma unroll
            for (int j = 0; j < 8; ++j) {
                int k = w * 256 + ks * 32 + lq * 8 + j;
                float v = Wh[(size_t)k * NG + zc];
                unsigned short h = f2bf(v);
                whh[nt][ks][j] = (short)h;
                lo[j] = (short)f2bf(v - bf2f(h));
            }
            whl_lds[w][nt][ks][lane] = lo;
        }
    }

    // ---- per-thread epilogue state: threads 0..127 own 2 cells each ----
    // Block owns 16 batches x 16 h-cols = 256 cells. Wave 0 = batches
    // [16g, 16g+8), wave 1 = [16g+8, 16g+16) -> per-wave flag covers a
    // clean batch half; consumers need BOTH flags of each producer.
    const int et     = tid & 127;
    const int bloc   = et >> 3;          // batch-in-group 0..15
    const int prc    = et & 7;           // col-pair 0..7 (block owns 16 cols)
    const int gbatch = g * 16 + bloc;
    const int colp   = bi * 16 + prc * 2; // first col of the pair
    float bgate[2][4];
    #pragma unroll
    for (int j = 0; j < 2; ++j)
        #pragma unroll
        for (int gt = 0; gt < 4; ++gt)
            bgate[j][gt] = bias[gt * NH + colp + j];
    float c2[2] = {0.0f, 0.0f};

    int* const gflags = flags + g * 128;          // 128 per-wave flags/group
    int* const myflag = gflags + bi * 2;          // +w added at publish
    unsigned int* const hpk32 = reinterpret_cast<unsigned int*>(hpack);

    // x fragments raw fp32, loaded one step ahead: [ks][half]
    f32x4 xr[4][2];
    {
        const float* xs = x + (size_t)(g * 16 + lm) * NT * NS + w * 128 + lq * 8;
        #pragma unroll
        for (int ks = 0; ks < 4; ++ks) {
            const f32x4* p = reinterpret_cast<const f32x4*>(xs + ks * 32);
            xr[ks][0] = p[0];
            xr[ks][1] = p[1];
        }
    }

    #pragma unroll 1
    for (int t = 0; t < NT; ++t) {
        // ---- wait for h_t: ONLY wave0 polls (r10: all-wave polling
        // saturates the coherence path). 128 flags/group read as 64 ull
        // pairs (r12-proven pattern). The poll's own waits also drain
        // wave0's x-prefetch; other waves drain at the release barrier. ----
        if (w == 0) {
            const unsigned long long* fp =
                reinterpret_cast<const unsigned long long*>(gflags);
            for (;;) {
                unsigned long long v = __hip_atomic_load(fp + lane, __ATOMIC_RELAXED,
                                                         __HIP_MEMORY_SCOPE_AGENT);
                int f0 = (int)(v & 0xffffffffu);
                int f1 = (int)(v >> 32);
                if (__all(f0 >= t && f1 >= t)) break;
                __builtin_amdgcn_s_sleep(1);
            }
            // no fence: h loads below are sc1 (coherent past L2)
        }
        __syncthreads();   // release; drains vmcnt for all waves

        // ---- issue h sc1 burst: 8 x dwordx4 (bf16-only, 8 elems each) ----
        const unsigned short* hb0 = hpack + (size_t)(t & 1) * (NB * NH)
                                  + (size_t)(g * 16 + lm) * NH + w * 256 + lq * 8;
        i32x4 q[8];
        GLD(q[0], hb0, 0);   GLD(q[1], hb0, 64);
        GLD(q[2], hb0, 128); GLD(q[3], hb0, 192);
        GLD(q[4], hb0, 256); GLD(q[5], hb0, 320);
        GLD(q[6], hb0, 384); GLD(q[7], hb0, 448);

        // ---- x-phase in the h-load shadow: hi/lo convert + 48 MFMAs ----
        f32x4 acc[4];
        #pragma unroll
        for (int nt = 0; nt < 4; ++nt) {
            acc[nt][0] = 0.f; acc[nt][1] = 0.f;
            acc[nt][2] = 0.f; acc[nt][3] = 0.f;
        }
        #pragma unroll
        for (int ks = 0; ks < 4; ++ks) {
            bf16x8 axh, axl;
            f32x4 vlo = xr[ks][0], vhi = xr[ks][1];
            #pragma unroll
            for (int j = 0; j < 4; ++j) {
                unsigned short h0 = f2bf(vlo[j]);
                axh[j]     = (short)h0;
                axl[j]     = (short)f2bf(vlo[j] - bf2f(h0));
                unsigned short h1 = f2bf(vhi[j]);
                axh[4 + j] = (short)h1;
                axl[4 + j] = (short)f2bf(vhi[j] - bf2f(h1));
            }
            #pragma unroll
            for (int nt = 0; nt < 4; ++nt) {
                acc[nt] = __builtin_amdgcn_mfma_f32_16x16x32_bf16(axh, wxh[nt][ks], acc[nt], 0, 0, 0);
                acc[nt] = __builtin_amdgcn_mfma_f32_16x16x32_bf16(axh, wxl[nt][ks], acc[nt], 0, 0, 0);
                acc[nt] = __builtin_amdgcn_mfma_f32_16x16x32_bf16(axl, wxh[nt][ks], acc[nt], 0, 0, 0);
            }
        }

        // ---- h-phase: chunked waits (8 outstanding), hi+lo MFMAs ----
        HKS(7, 0) HKS(6, 1) HKS(5, 2) HKS(4, 3)
        HKS(3, 4) HKS(2, 5) HKS(1, 6) HKS(0, 7)

        // ---- cross-wave K-reduction via LDS (D: row = lq*4+r, col = lm) ----
        #pragma unroll
        for (int nt = 0; nt < 4; ++nt)
            #pragma unroll
            for (int r = 0; r < 4; ++r)
                zl[w][nt][lq * 4 + r][lm] = acc[nt][r];
        __syncthreads();

        // ---- epilogue: threads 0..127 (waves 0,1) do 2 cells each;
        // each wave publishes its OWN flag after its OWN store-ack ----
        if (tid < 128) {
            float hv[2];
            #pragma unroll
            for (int j = 0; j < 2; ++j) {
                const int n = prc * 2 + j;
                float zg[4];
                #pragma unroll
                for (int gt = 0; gt < 4; ++gt) {
                    zg[gt] = zl[0][gt][bloc][n] + zl[1][gt][bloc][n]
                           + zl[2][gt][bloc][n] + zl[3][gt][bloc][n]
                           + bgate[j][gt];
                }
                // Keras gate order: i, f, g, o
                float ig = sigm(zg[0]);
                float fg = sigm(zg[1]);
                float gg = tanh_f(zg[2]);
                float og = sigm(zg[3]);
                c2[j] = fg * c2[j] + ig * gg;
                hv[j] = og * tanh_f(c2[j]);
            }
            // pack two adjacent cols into one u32 (little-endian: low = colp)
            unsigned pk = (unsigned)f2bf(hv[0]) | ((unsigned)f2bf(hv[1]) << 16);
            const size_t po = (size_t)((t + 1) & 1) * (NB * NH / 2)
                            + (size_t)gbatch * (NH / 2) + bi * 8 + prc;
            __hip_atomic_store(hpk32 + po, pk, __ATOMIC_RELAXED, __HIP_MEMORY_SCOPE_AGENT);
            if (t == NT - 1) {
                hF32[(size_t)gbatch * NH + colp]     = hv[0];
                hF32[(size_t)gbatch * NH + colp + 1] = hv[1];
            }
            // per-wave publish: drain THIS wave's h-stores (agent-scope,
            // ack'd at the coherence point), then lane 0 sets flag.
            asm volatile("s_waitcnt vmcnt(0)" ::: "memory");
            if ((tid & 63) == 0)
                __hip_atomic_store(myflag + w, t + 1, __ATOMIC_RELAXED,
                                   __HIP_MEMORY_SCOPE_AGENT);
        }

        // ---- x-prefetch for t+1 AFTER publish (waves 0,1) / after zl
        // barrier (waves 2,3 — no publish duty, can't delay a flag).
        // Drained by wave0's next poll / the next release barrier. ----
        if (t + 1 < NT) {
            const float* xs = x + ((size_t)(g * 16 + lm) * NT + (t + 1)) * NS
                                + w * 128 + lq * 8;
            #pragma unroll
            for (int ks = 0; ks < 4; ++ks) {
                const f32x4* p = reinterpret_cast<const f32x4*>(xs + ks * 32);
                xr[ks][0] = p[0];
                xr[ks][1] = p[1];
            }
        }
        // NOTE: no end-of-loop barrier. zl safety: next-iteration zl
        // writes happen after the release barrier, which waves 0,1 only
        // reach after their epilogue zl-reads completed.
    }
}

// hid = relu(hF32 @ Wd1 + bd1)   [64,1024]x[1024,512]
// r15: 64 blocks x 512 threads (1 batch/block, thread = output col).
// Wd1 L2 traffic: 64 x 2 MB = 128 MB (was 256 MB); 8-deep ILP chain.
__global__ __launch_bounds__(512) void head1(
    const float* __restrict__ hF32, const float* __restrict__ Wd1,
    const float* __restrict__ bd1, float* __restrict__ hid)
{
    int b = blockIdx.x;
    int n = threadIdx.x;
    const float* hrow = hF32 + (size_t)b * NH;
    float acc = bd1[n];
    #pragma unroll 8
    for (int k = 0; k < NH; ++k)
        acc += hrow[k] * Wd1[(size_t)k * NHD + n];
    hid[(size_t)b * NHD + n] = fmaxf(acc, 0.0f);
}

// out = [hid | actions | horizon] @ Wd2 + bd2   K = 512 + 64 + 1 = 577
// r15: 64 blocks x 256 threads; K split 4-way across thread groups +
// LDS reduce (was 64x64 = 16 waves device-wide, serial K=577).
__global__ __launch_bounds__(256) void head2(
    const float* __restrict__ hid, const float* __restrict__ act,
    const float* __restrict__ hor, const float* __restrict__ Wd2,
    const float* __restrict__ bd2, float* __restrict__ out)
{
    __shared__ float red[4][64];
    int b  = blockIdx.x;
    int n  = threadIdx.x & 63;
    int ks = threadIdx.x >> 6;    // 0..3
    const float* hrow = hid + (size_t)b * NHD;
    float acc = 0.0f;
    #pragma unroll 4
    for (int k = ks * 128; k < ks * 128 + 128; ++k)
        acc += hrow[k] * Wd2[(size_t)k * NO + n];
    if (ks == 1) {
        const float* arow = act + (size_t)b * NA;
        #pragma unroll 4
        for (int k = 0; k < NA; ++k)
            acc += arow[k] * Wd2[(size_t)(NHD + k) * NO + n];
    }
    if (ks == 2) acc += hor[b] * Wd2[(size_t)576 * NO + n];
    if (ks == 0) acc += bd2[n];
    red[ks][n] = acc;
    __syncthreads();
    if (threadIdx.x < 64)
        out[(size_t)b * NO + n] = red[0][n] + red[1][n] + red[2][n] + red[3][n];
}

extern "C" void kernel_launch(void* const* d_in, const int* in_sizes, int n_in,
                              void* d_out, int out_size, void* d_ws, size_t ws_size,
                              hipStream_t stream)
{
    (void)in_sizes; (void)n_in; (void)out_size; (void)ws_size;
    const float* x    = (const float*)d_in[0];
    const float* act  = (const float*)d_in[1];
    const float* hor  = (const float*)d_in[2];
    const float* Wx   = (const float*)d_in[3];
    const float* Wh   = (const float*)d_in[4];
    const float* bias = (const float*)d_in[5];
    const float* Wd1  = (const float*)d_in[6];
    const float* bd1  = (const float*)d_in[7];
    const float* Wd2  = (const float*)d_in[8];
    const float* bd2  = (const float*)d_in[9];
    float* out = (float*)d_out;

    char* wsb = (char*)d_ws;
    unsigned short* hpk = (unsigned short*)(wsb + WS_HPK);
    float* hF32 = (float*)(wsb + WS_HF32);
    float* hid  = (float*)(wsb + WS_HID);
    int*   flg  = (int*)(wsb + WS_FLG);

    prologue<<<256, 256, 0, stream>>>((unsigned int*)(wsb + WS_HPK),
                                      (unsigned int*)(wsb + WS_FLG));

    // Plain launch (NOT cooperative — see r2 post-mortem). 256 blocks == 256 CUs.
    lstm_persist<<<dim3(256), dim3(256), 0, stream>>>(x, Wx, Wh, bias,
                                                      hpk, hF32, flg);

    head1<<<64, 512, 0, stream>>>(hF32, Wd1, bd1, hid);
    head2<<<64, 256, 0, stream>>>(hid, act, hor, Wd2, bd2, out);
}

// Round 5
// 1432.002 us; speedup vs baseline: 1.3066x; 1.3066x over previous
//
#include <hip/hip_runtime.h>
#include <stdint.h>

// Problem dims
#define NB   64      // batch
#define NT   256     // timesteps
#define NS   512     // input feature (state)
#define NH   1024    // hidden
#define NG   4096    // 4*NH (gates)
#define NHD  512     // dense1 width
#define NA   64      // action size
#define NO   64      // n_output

typedef float f32x4  __attribute__((ext_vector_type(4)));
typedef short bf16x8 __attribute__((ext_vector_type(8)));
typedef int   i32x4  __attribute__((ext_vector_type(4)));

__device__ __forceinline__ unsigned short f2bf(float f) {
    union { float f; unsigned u; } a; a.f = f;
    unsigned u = a.u;
    return (unsigned short)((u + 0x7fffu + ((u >> 16) & 1u)) >> 16);   // RNE
}
__device__ __forceinline__ float bf2f(unsigned short h) {
    union { unsigned u; float f; } a; a.u = ((unsigned)h) << 16; return a.f;
}
__device__ __forceinline__ float sigm(float x) {
    return __fdividef(1.0f, 1.0f + __expf(-x));
}
__device__ __forceinline__ float tanh_f(float x) {
    float e = __expf(-2.0f * fabsf(x));
    float r = __fdividef(1.0f - e, 1.0f + e);
    return x >= 0.0f ? r : -r;
}

// sc1 load: bypasses the non-coherent per-XCD L2 -> reads the coherence point.
#define GLD(dst, base, off) \
    asm volatile("global_load_dwordx4 %0, %1, off offset:" #off " sc1" \
                 : "=v"(dst) : "v"(base) : "memory")

// h-phase chunk (r13 layout: 1 m-tile, 4 n-tiles, Wh-lo from LDS).
// 8 h loads outstanding at phase start; chunk ks retired at vmcnt <= 7-ks.
// whh from VGPR; whl read per-chunk from LDS (4x ds_read_b128, hidden
// behind the inter-chunk sc1 return gaps; compiler inserts the lgkmcnt
// before MFMA use). The vmcnt asm ties q[ks] so the dependent MFMAs
// can't hoist above it. No #pragma in macro bodies (r6).
#define HKS(WN, ks)                                                              \
    {                                                                            \
        asm volatile("s_waitcnt vmcnt(" #WN ")" : "+v"(q[ks]));                  \
        union { i32x4 i; bf16x8 v; } u0; u0.i = q[ks];                           \
        bf16x8 fh = u0.v;                                                        \
        bf16x8 l0 = whl_lds[w][0][ks][lane];                                     \
        bf16x8 l1 = whl_lds[w][1][ks][lane];                                     \
        bf16x8 l2 = whl_lds[w][2][ks][lane];                                     \
        bf16x8 l3 = whl_lds[w][3][ks][lane];                                     \
        acc[0] = __builtin_amdgcn_mfma_f32_16x16x32_bf16(fh, whh[0][ks], acc[0], 0, 0, 0); \
        acc[1] = __builtin_amdgcn_mfma_f32_16x16x32_bf16(fh, whh[1][ks], acc[1], 0, 0, 0); \
        acc[2] = __builtin_amdgcn_mfma_f32_16x16x32_bf16(fh, whh[2][ks], acc[2], 0, 0, 0); \
        acc[3] = __builtin_amdgcn_mfma_f32_16x16x32_bf16(fh, whh[3][ks], acc[3], 0, 0, 0); \
        acc[0] = __builtin_amdgcn_mfma_f32_16x16x32_bf16(fh, l0, acc[0], 0, 0, 0); \
        acc[1] = __builtin_amdgcn_mfma_f32_16x16x32_bf16(fh, l1, acc[1], 0, 0, 0); \
        acc[2] = __builtin_amdgcn_mfma_f32_16x16x32_bf16(fh, l2, acc[2], 0, 0, 0); \
        acc[3] = __builtin_amdgcn_mfma_f32_16x16x32_bf16(fh, l3, acc[3], 0, 0, 0); \
    }

// Workspace layout (bytes):
//   [0)       hpk : 2 x 64 x 1024 bf16 = 262144  (h bf16-only, dbl-buffered)
//   [262144)  hF32: 64 x 1024 f32      = 262144
//   [524288)  hid : 64 x 512 f32       = 131072
//   [655360)  flags: 4 groups x 64 i32 = 1024
#define WS_HPK   0
#define WS_HF32  262144
#define WS_HID   524288
#define WS_FLG   655360

__global__ void prologue(unsigned int* __restrict__ hpk32,
                         unsigned int* __restrict__ flg32) {
    int idx = blockIdx.x * blockDim.x + threadIdx.x;   // 65536 threads
    hpk32[idx] = 0u;            // 65536 u32 = 131072 bf16 = both parities
    if (idx < 256) flg32[idx] = 0u;
}

// Persistent LSTM recurrence. Weights & x: double-bf16 hi/lo (exact);
// h exchange: bf16-ONLY (r12). 4 groups x 64 blocks (r13/r14, measured
// 5.37 us/step).
// r16 (resubmitted r17 — round-4 was a container/infra failure, kernel
// never ran; same signature as round-1): EXACT r14 protocol restored.
// r15's per-wave early publish REGRESSED (+1.6 us/step): waves 2,3
// issued x-prefetch during the publish window, queueing the h-store ack
// behind 8 KB of prefetch on the shared vmem/L2 path — and the step is
// globally gated on the slowest producer's publish. LESSON (r11, r15):
// ALL vmem must be silent around the publish; prefetch goes strictly
// AFTER the flag.
// Group g: batches [16g,16g+16) (ONE m-tile); block bi: h-cols
// [16bi,16bi+16) x 4 gates as 4 n-tiles (nt == gate); wave w: K-slice.
// Weight storage: whh+wx hi/lo in VGPR (256); Wh-lo frags in LDS (128 KB,
// same-wave same-lane write/read -> no barrier).
// PLAIN launch (cooperative fails silently — r2). 256 blocks == 256 CUs;
// 145 KiB LDS forces 1 block/CU.
__global__ __launch_bounds__(256, 1) void lstm_persist(
    const float* __restrict__ x, const float* __restrict__ Wx,
    const float* __restrict__ Wh, const float* __restrict__ bias,
    unsigned short* __restrict__ hpack, float* __restrict__ hF32,
    int* __restrict__ flags)
{
    const int g    = blockIdx.x >> 6;    // group 0..3
    const int bi   = blockIdx.x & 63;    // block-in-group 0..63
    const int tid  = threadIdx.x;
    const int w    = tid >> 6;
    const int lane = tid & 63;
    const int lm   = lane & 15;   // A: m(batch row) ; B: n ; D: col
    const int lq   = lane >> 4;   // k-quad

    // Wh-lo fragments: [wave][nt][ks][lane] of bf16x8 = 128 KiB.
    // Each wave reads ONLY its own [w] slice -> no barrier needed.
    __shared__ bf16x8 whl_lds[4][4][8][64];
    __shared__ float zl[4][4][16][17];   // [wave][nt][row][col] (+1 pad)

    // ---- one-time: weight B-fragments into registers / LDS ----
    // B-frag (16x16x32): lane holds B[k = lq*8 + j][n = lm], j = 0..7
    bf16x8 wxh[4][4], wxl[4][4];   // [nt][kstep] x-path, K=512/4waves
    bf16x8 whh[4][8];              // [nt][kstep] h-path hi, K=1024/4waves
    #pragma unroll
    for (int nt = 0; nt < 4; ++nt) {
        const int zc = nt * NH + bi * 16 + lm;   // nt == gate
        #pragma unroll
        for (int ks = 0; ks < 4; ++ks)
            #pragma unroll
            for (int j = 0; j < 8; ++j) {
                int k = w * 128 + ks * 32 + lq * 8 + j;
                float v = Wx[(size_t)k * NG + zc];
                unsigned short h = f2bf(v);
                wxh[nt][ks][j] = (short)h;
                wxl[nt][ks][j] = (short)f2bf(v - bf2f(h));
            }
        #pragma unroll
        for (int ks = 0; ks < 8; ++ks) {
            bf16x8 lo;
            #pragma unroll
            for (int j = 0; j < 8; ++j) {
                int k = w * 256 + ks * 32 + lq * 8 + j;
                float v = Wh[(size_t)k * NG + zc];
                unsigned short h = f2bf(v);
                whh[nt][ks][j] = (short)h;
                lo[j] = (short)f2bf(v - bf2f(h));
            }
            whl_lds[w][nt][ks][lane] = lo;
        }
    }

    // ---- per-thread epilogue state: threads 0..127 own 2 cells each ----
    // Block owns 16 batches x 16 h-cols = 256 cells.
    const int et     = tid & 127;
    const int bloc   = et >> 3;          // batch-in-group 0..15
    const int prc    = et & 7;           // col-pair 0..7 (block owns 16 cols)
    const int gbatch = g * 16 + bloc;
    const int colp   = bi * 16 + prc * 2; // first col of the pair
    float bgate[2][4];
    #pragma unroll
    for (int j = 0; j < 2; ++j)
        #pragma unroll
        for (int gt = 0; gt < 4; ++gt)
            bgate[j][gt] = bias[gt * NH + colp + j];
    float c2[2] = {0.0f, 0.0f};

    int* const gflags = flags + g * 64;
    int* const myflag = gflags + bi;
    unsigned int* const hpk32 = reinterpret_cast<unsigned int*>(hpack);

    // x fragments raw fp32, loaded one step ahead: [ks][half]
    f32x4 xr[4][2];
    {
        const float* xs = x + (size_t)(g * 16 + lm) * NT * NS + w * 128 + lq * 8;
        #pragma unroll
        for (int ks = 0; ks < 4; ++ks) {
            const f32x4* p = reinterpret_cast<const f32x4*>(xs + ks * 32);
            xr[ks][0] = p[0];
            xr[ks][1] = p[1];
        }
    }

    #pragma unroll 1
    for (int t = 0; t < NT; ++t) {
        // ---- wait for h_t: ONLY wave0 polls (256 pollers device-wide;
        // all-wave polling saturates the coherence path — r10). 64 flags
        // per group -> one 4B flag per lane. The poll's own waits also
        // drain the x loads issued after last publish. ----
        if (w == 0) {
            const int* fp = gflags + lane;
            for (;;) {
                int v = __hip_atomic_load(fp, __ATOMIC_RELAXED,
                                          __HIP_MEMORY_SCOPE_AGENT);
                if (__all(v >= t)) break;
                __builtin_amdgcn_s_sleep(1);
            }
            // no fence: h loads below are sc1 (coherent past L2)
        }
        __syncthreads();   // drains vmcnt for all waves

        // ---- issue h sc1 burst: 8 x dwordx4 (bf16-only, 8 elems each) ----
        const unsigned short* hb0 = hpack + (size_t)(t & 1) * (NB * NH)
                                  + (size_t)(g * 16 + lm) * NH + w * 256 + lq * 8;
        i32x4 q[8];
        GLD(q[0], hb0, 0);   GLD(q[1], hb0, 64);
        GLD(q[2], hb0, 128); GLD(q[3], hb0, 192);
        GLD(q[4], hb0, 256); GLD(q[5], hb0, 320);
        GLD(q[6], hb0, 384); GLD(q[7], hb0, 448);

        // ---- x-phase in the h-load shadow: hi/lo convert + 48 MFMAs ----
        f32x4 acc[4];
        #pragma unroll
        for (int nt = 0; nt < 4; ++nt) {
            acc[nt][0] = 0.f; acc[nt][1] = 0.f;
            acc[nt][2] = 0.f; acc[nt][3] = 0.f;
        }
        #pragma unroll
        for (int ks = 0; ks < 4; ++ks) {
            bf16x8 axh, axl;
            f32x4 vlo = xr[ks][0], vhi = xr[ks][1];
            #pragma unroll
            for (int j = 0; j < 4; ++j) {
                unsigned short h0 = f2bf(vlo[j]);
                axh[j]     = (short)h0;
                axl[j]     = (short)f2bf(vlo[j] - bf2f(h0));
                unsigned short h1 = f2bf(vhi[j]);
                axh[4 + j] = (short)h1;
                axl[4 + j] = (short)f2bf(vhi[j] - bf2f(h1));
            }
            #pragma unroll
            for (int nt = 0; nt < 4; ++nt) {
                acc[nt] = __builtin_amdgcn_mfma_f32_16x16x32_bf16(axh, wxh[nt][ks], acc[nt], 0, 0, 0);
                acc[nt] = __builtin_amdgcn_mfma_f32_16x16x32_bf16(axh, wxl[nt][ks], acc[nt], 0, 0, 0);
                acc[nt] = __builtin_amdgcn_mfma_f32_16x16x32_bf16(axl, wxh[nt][ks], acc[nt], 0, 0, 0);
            }
        }

        // ---- h-phase: chunked waits (8 outstanding), hi+lo MFMAs ----
        HKS(7, 0) HKS(6, 1) HKS(5, 2) HKS(4, 3)
        HKS(3, 4) HKS(2, 5) HKS(1, 6) HKS(0, 7)

        // ---- cross-wave K-reduction via LDS (D: row = lq*4+r, col = lm) ----
        #pragma unroll
        for (int nt = 0; nt < 4; ++nt)
            #pragma unroll
            for (int r = 0; r < 4; ++r)
                zl[w][nt][lq * 4 + r][lm] = acc[nt][r];
        __syncthreads();

        // ---- epilogue: threads 0..127 (waves 0,1) do 2 cells each ----
        if (tid < 128) {
            float hv[2];
            #pragma unroll
            for (int j = 0; j < 2; ++j) {
                const int n = prc * 2 + j;
                float zg[4];
                #pragma unroll
                for (int gt = 0; gt < 4; ++gt) {
                    zg[gt] = zl[0][gt][bloc][n] + zl[1][gt][bloc][n]
                           + zl[2][gt][bloc][n] + zl[3][gt][bloc][n]
                           + bgate[j][gt];
                }
                // Keras gate order: i, f, g, o
                float ig = sigm(zg[0]);
                float fg = sigm(zg[1]);
                float gg = tanh_f(zg[2]);
                float og = sigm(zg[3]);
                c2[j] = fg * c2[j] + ig * gg;
                hv[j] = og * tanh_f(c2[j]);
            }
            // pack two adjacent cols into one u32 (little-endian: low = colp)
            unsigned pk = (unsigned)f2bf(hv[0]) | ((unsigned)f2bf(hv[1]) << 16);
            const size_t po = (size_t)((t + 1) & 1) * (NB * NH / 2)
                            + (size_t)gbatch * (NH / 2) + bi * 8 + prc;
            __hip_atomic_store(hpk32 + po, pk, __ATOMIC_RELAXED, __HIP_MEMORY_SCOPE_AGENT);
            if (t == NT - 1) {
                hF32[(size_t)gbatch * NH + colp]     = hv[0];
                hF32[(size_t)gbatch * NH + colp + 1] = hv[1];
            }
        }

        // ---- publish: syncthreads drains vmcnt (h store at coherence point),
        // then relaxed flag store — no fences ----
        __syncthreads();
        if (tid == 0)
            __hip_atomic_store(myflag, t + 1, __ATOMIC_RELAXED, __HIP_MEMORY_SCOPE_AGENT);

        // ---- x-prefetch for t+1 AFTER publish (r8 placement: flies during
        // the spin window; drained by the next poll/barrier) ----
        if (t + 1 < NT) {
            const float* xs = x + ((size_t)(g * 16 + lm) * NT + (t + 1)) * NS
                                + w * 128 + lq * 8;
            #pragma unroll
            for (int ks = 0; ks < 4; ++ks) {
                const f32x4* p = reinterpret_cast<const f32x4*>(xs + ks * 32);
                xr[ks][0] = p[0];
                xr[ks][1] = p[1];
            }
        }
    }
}

// hid = relu(hF32 @ Wd1 + bd1)   [64,1024]x[1024,512]
// r15 heads kept (measured good: non-lstm time 125 -> 91 us).
// 64 blocks x 512 threads (1 batch/block, thread = output col).
__global__ __launch_bounds__(512) void head1(
    const float* __restrict__ hF32, const float* __restrict__ Wd1,
    const float* __restrict__ bd1, float* __restrict__ hid)
{
    int b = blockIdx.x;
    int n = threadIdx.x;
    const float* hrow = hF32 + (size_t)b * NH;
    float acc = bd1[n];
    #pragma unroll 8
    for (int k = 0; k < NH; ++k)
        acc += hrow[k] * Wd1[(size_t)k * NHD + n];
    hid[(size_t)b * NHD + n] = fmaxf(acc, 0.0f);
}

// out = [hid | actions | horizon] @ Wd2 + bd2   K = 512 + 64 + 1 = 577
// 64 blocks x 256 threads; K split 4-way across thread groups + LDS reduce.
__global__ __launch_bounds__(256) void head2(
    const float* __restrict__ hid, const float* __restrict__ act,
    const float* __restrict__ hor, const float* __restrict__ Wd2,
    const float* __restrict__ bd2, float* __restrict__ out)
{
    __shared__ float red[4][64];
    int b  = blockIdx.x;
    int n  = threadIdx.x & 63;
    int ks = threadIdx.x >> 6;    // 0..3
    const float* hrow = hid + (size_t)b * NHD;
    float acc = 0.0f;
    #pragma unroll 4
    for (int k = ks * 128; k < ks * 128 + 128; ++k)
        acc += hrow[k] * Wd2[(size_t)k * NO + n];
    if (ks == 1) {
        const float* arow = act + (size_t)b * NA;
        #pragma unroll 4
        for (int k = 0; k < NA; ++k)
            acc += arow[k] * Wd2[(size_t)(NHD + k) * NO + n];
    }
    if (ks == 2) acc += hor[b] * Wd2[(size_t)576 * NO + n];
    if (ks == 0) acc += bd2[n];
    red[ks][n] = acc;
    __syncthreads();
    if (threadIdx.x < 64)
        out[(size_t)b * NO + n] = red[0][n] + red[1][n] + red[2][n] + red[3][n];
}

extern "C" void kernel_launch(void* const* d_in, const int* in_sizes, int n_in,
                              void* d_out, int out_size, void* d_ws, size_t ws_size,
                              hipStream_t stream)
{
    (void)in_sizes; (void)n_in; (void)out_size; (void)ws_size;
    const float* x    = (const float*)d_in[0];
    const float* act  = (const float*)d_in[1];
    const float* hor  = (const float*)d_in[2];
    const float* Wx   = (const float*)d_in[3];
    const float* Wh   = (const float*)d_in[4];
    const float* bias = (const float*)d_in[5];
    const float* Wd1  = (const float*)d_in[6];
    const float* bd1  = (const float*)d_in[7];
    const float* Wd2  = (const float*)d_in[8];
    const float* bd2  = (const float*)d_in[9];
    float* out = (float*)d_out;

    char* wsb = (char*)d_ws;
    unsigned short* hpk = (unsigned short*)(wsb + WS_HPK);
    float* hF32 = (float*)(wsb + WS_HF32);
    float* hid  = (float*)(wsb + WS_HID);
    int*   flg  = (int*)(wsb + WS_FLG);

    prologue<<<256, 256, 0, stream>>>((unsigned int*)(wsb + WS_HPK),
                                      (unsigned int*)(wsb + WS_FLG));

    // Plain launch (NOT cooperative — see r2 post-mortem). 256 blocks == 256 CUs.
    lstm_persist<<<dim3(256), dim3(256), 0, stream>>>(x, Wx, Wh, bias,
                                                      hpk, hF32, flg);

    head1<<<64, 512, 0, stream>>>(hF32, Wd1, bd1, hid);
    head2<<<64, 256, 0, stream>>>(hid, act, hor, Wd2, bd2, out);
}